// Round 4
// baseline (320.603 us; speedup 1.0000x reference)
//
#include <hip/hip_runtime.h>

#define HW 512
#define NPIX (HW * HW)        // 262144 pixels, u8 table = 256 KB (L2-resident per XCD)
#define THREADS 256           // 4 waves/block
#define BLOCKS 2048           // 8 blocks/CU -> 32 waves/CU (8/SIMD) — 2x the LDS design
#define NB 2                  // elements per round (small state -> fits 64-VGPR budget)
#define RNDS 8                // 2*8 = 16 elems/thread; 2048*256*16 = 8388608 = N

// Reference constants
#define EPS_F  1e-10f
constexpr double B_d  = 1.0 + 0.1 + 0.05;        // 1.15
constexpr double BR_d = 1.0 + 0.1 - 0.05;        // 1.05
#define B_F    ((float)B_d)
#define INVB_F ((float)(1.0 / B_d))
#define BR_F   ((float)BR_d)
#define BL_F   ((float)(1.0 / BR_d))

typedef __attribute__((ext_vector_type(4))) int ivec4;

// u8 table: k = round(m*255), v = (k+1)/256. |dv| <= 1/512; measured final
// absmax 1.95e-3 vs threshold 7.07e-3.
__global__ void build_v(const float* __restrict__ vin,
                        unsigned char* __restrict__ vq,
                        float* __restrict__ out) {
    int i = blockIdx.x * blockDim.x + threadIdx.x;
    if (i == 0) *out = 0.0f;                     // fold d_out zero-init here
    if (i < NPIX) {
        float s = vin[i] + vin[i + NPIX] + vin[i + 2 * NPIX];
        float m = s * (1.0f / 3.0f);
        vq[i] = (unsigned char)__float2int_rn(m * 255.0f);
    }
}

__device__ __forceinline__ float rcp_fast(float x) {
#if __has_builtin(__builtin_amdgcn_rcpf)
    return __builtin_amdgcn_rcpf(x);             // v_rcp_f32, ~1 ulp — margin is 3.6x
#else
    return 1.0f / x;
#endif
}

__device__ __forceinline__ float per_loss(float r1, float r2, int d) {
    float ratio = r1 * rcp_fast(r2 + EPS_F);
    float rinv  = r2 * rcp_fast(r1 + EPS_F);
    float l1 = (ratio > INVB_F) ? (ratio - INVB_F + (B_F - rinv)) : 0.0f;
    float l2 = (ratio < B_F)    ? (B_F - ratio + (rinv - INVB_F)) : 0.0f;
    float l0 = (ratio > BR_F)   ? (ratio - BR_F + (BL_F - rinv))
             : ((ratio < BL_F)  ? (BL_F - ratio + (rinv - BR_F)) : 0.0f);
    return (d == 1) ? l1 : ((d == 2) ? l2 : l0);
}

// One pipelined round: addrs -> issue gathers (L2-cached, NOT nontemporal) ->
// prefetch coords(r+2) -> consume (counted vmcnt leaves prefetches in flight)
// -> prefetch darker/weights(r+2) after their round-r values are consumed.
// Latency hiding comes from 8 waves/SIMD interleaving, not program distance.
template<bool PF>
__device__ __forceinline__ void do_round(
        ivec4 (&cc)[NB], int (&dd)[NB], float (&ww)[NB],
        const unsigned char* __restrict__ vq,
        const ivec4* __restrict__ coords, const int* __restrict__ darker,
        const float* __restrict__ weights,
        int tid, int T, int pfofs, float& acc)
{
    int i1[NB], i2[NB];
    unsigned q1[NB], q2[NB];
    #pragma unroll
    for (int k = 0; k < NB; ++k) {
        i1[k] = cc[k].y * HW + cc[k].x;
        i2[k] = cc[k].w * HW + cc[k].z;
    }
    #pragma unroll
    for (int k = 0; k < NB; ++k) {               // all-global gathers (table in L2)
        q1[k] = vq[i1[k]];
        q2[k] = vq[i2[k]];
    }
    if (PF) {
        #pragma unroll
        for (int k = 0; k < NB; ++k)
            cc[k] = __builtin_nontemporal_load(&coords[tid + (pfofs + k) * T]);
    }
    __builtin_amdgcn_sched_barrier(0);           // keep prefetch issue above consume
    #pragma unroll
    for (int k = 0; k < NB; ++k) {
        float r1 = (float)(q1[k] + 1) * (1.0f / 256.0f);
        float r2 = (float)(q2[k] + 1) * (1.0f / 256.0f);
        acc += ww[k] * per_loss(r1, r2, dd[k]);
    }
    if (PF) {
        #pragma unroll
        for (int k = 0; k < NB; ++k)
            dd[k] = __builtin_nontemporal_load(&darker[tid + (pfofs + k) * T]);
        #pragma unroll
        for (int k = 0; k < NB; ++k)
            ww[k] = __builtin_nontemporal_load(&weights[tid + (pfofs + k) * T]);
        __builtin_amdgcn_sched_barrier(0);       // don't sink into next round's consume
    }
}

// __launch_bounds__(256, 8): 8 waves/EU -> 8 blocks/CU = 32 waves/CU, VGPR
// budget 64/wave. NB=2 keeps live state ~55 regs so it fits without spilling
// (R2 lesson: the compiler WILL spill silently — check WRITE_SIZE if visible).
// No LDS table: the 160 KB LDS slice capped us at 4 waves/SIMD, which was the
// real bottleneck (R0/R1/R3 all ~72 us regardless of schedule, nothing busy).
__global__ __launch_bounds__(THREADS, 8) void whdr_kernel(
        const unsigned char* __restrict__ vq,
        const ivec4* __restrict__ coords,
        const int*   __restrict__ darker,
        const float* __restrict__ weights,
        float*       __restrict__ out,
        int n) {
    const int tid = blockIdx.x * THREADS + threadIdx.x;
    const int T   = BLOCKS * THREADS;            // 524288
    float acc = 0.0f;

    if (n == T * NB * RNDS) {
        // ---- steady-state pipelined path (exact fit, all threads) ----
        ivec4 cA[NB], cB[NB];
        int   dA[NB], dB[NB];
        float wA[NB], wB[NB];
        // Prologue: rounds 0 and 1 in flight.
        #pragma unroll
        for (int k = 0; k < NB; ++k) cA[k] = __builtin_nontemporal_load(&coords[tid + k * T]);
        #pragma unroll
        for (int k = 0; k < NB; ++k) dA[k] = __builtin_nontemporal_load(&darker[tid + k * T]);
        #pragma unroll
        for (int k = 0; k < NB; ++k) wA[k] = __builtin_nontemporal_load(&weights[tid + k * T]);
        #pragma unroll
        for (int k = 0; k < NB; ++k) cB[k] = __builtin_nontemporal_load(&coords[tid + (NB + k) * T]);
        #pragma unroll
        for (int k = 0; k < NB; ++k) dB[k] = __builtin_nontemporal_load(&darker[tid + (NB + k) * T]);
        #pragma unroll
        for (int k = 0; k < NB; ++k) wB[k] = __builtin_nontemporal_load(&weights[tid + (NB + k) * T]);

#define RPF(r, S) do_round<true >(c##S, d##S, w##S, vq, coords, darker, weights, tid, T, (r + 2) * NB, acc)
#define RNP(S)    do_round<false>(c##S, d##S, w##S, vq, coords, darker, weights, tid, T, 0, acc)
        RPF(0, A); RPF(1, B); RPF(2, A); RPF(3, B);
        RPF(4, A); RPF(5, B); RNP(A);    RNP(B);
#undef RPF
#undef RNP
    } else {
        // ---- generic fallback (any n) ----
        const int TT = gridDim.x * THREADS;
        for (int i = tid; i < n; i += TT) {
            ivec4 c = coords[i];
            unsigned a = vq[c.y * HW + c.x];
            unsigned b = vq[c.w * HW + c.z];
            float r1 = (float)(a + 1) * (1.0f / 256.0f);
            float r2 = (float)(b + 1) * (1.0f / 256.0f);
            acc += weights[i] * per_loss(r1, r2, darker[i]);
        }
    }

    // wave-64 shuffle reduction, then tiny LDS block reduction (4 waves)
    #pragma unroll
    for (int off = 32; off > 0; off >>= 1)
        acc += __shfl_down(acc, off, 64);
    __shared__ float wsum[THREADS / 64];
    int lane = threadIdx.x & 63;
    int wid  = threadIdx.x >> 6;
    if (lane == 0) wsum[wid] = acc;
    __syncthreads();
    if (threadIdx.x == 0) {
        float s = 0.0f;
        #pragma unroll
        for (int i = 0; i < THREADS / 64; ++i) s += wsum[i];
        atomicAdd(out, s / (float)n);            // n = 2^23 -> exact
    }
}

extern "C" void kernel_launch(void* const* d_in, const int* in_sizes, int n_in,
                              void* d_out, int out_size, void* d_ws, size_t ws_size,
                              hipStream_t stream) {
    const float* v_input = (const float*)d_in[0];  // (3,512,512) f32
    const ivec4* coords  = (const ivec4*)d_in[1];  // (N,4) i32
    const int*   darker  = (const int*)d_in[2];    // (N,) i32
    const float* weights = (const float*)d_in[3];  // (N,) f32
    float* out = (float*)d_out;
    unsigned char* vq = (unsigned char*)d_ws;      // 256 KB u8 v table
    int n = in_sizes[2];                           // N

    build_v<<<(NPIX + 255) / 256, 256, 0, stream>>>(v_input, vq, out);
    whdr_kernel<<<BLOCKS, THREADS, 0, stream>>>(vq, coords, darker, weights, out, n);
}

// Round 5
// 246.652 us; speedup vs baseline: 1.2998x; 1.2998x over previous
//
#include <hip/hip_runtime.h>

#define HW 512
#define NPIX (HW * HW)        // 262144 pixels
#define LDS_PIX 163840        // 160 KB u8 slice in LDS (62.5% of table)
#define THREADS 1024          // 16 waves/block, 1 block/CU (LDS-capped)
#define BLOCKS 512
#define NB 4                  // elems per round; 4 rounds -> 16/thread; 512*1024*16 = N

// Reference constants
#define EPS_F  1e-10f
constexpr double B_d  = 1.0 + 0.1 + 0.05;        // 1.15
constexpr double BR_d = 1.0 + 0.1 - 0.05;        // 1.05
#define B_F    ((float)B_d)
#define INVB_F ((float)(1.0 / B_d))
#define BR_F   ((float)BR_d)
#define BL_F   ((float)(1.0 / BR_d))

typedef __attribute__((ext_vector_type(4))) int ivec4;

// u8 table: k = round(m*255), v = (k+1)/256. |dv| <= 1/512; measured final
// absmax 1.95e-3 vs threshold 7.07e-3.
__global__ void build_v(const float* __restrict__ vin,
                        unsigned char* __restrict__ vq,
                        float* __restrict__ out) {
    int i = blockIdx.x * blockDim.x + threadIdx.x;
    if (i == 0) *out = 0.0f;                     // fold d_out zero-init here
    if (i < NPIX) {
        float s = vin[i] + vin[i + NPIX] + vin[i + 2 * NPIX];
        float m = s * (1.0f / 3.0f);
        vq[i] = (unsigned char)__float2int_rn(m * 255.0f);
    }
}

__device__ __forceinline__ float rcp_fast(float x) {
#if __has_builtin(__builtin_amdgcn_rcpf)
    return __builtin_amdgcn_rcpf(x);             // v_rcp_f32, ~1 ulp — margin is 3.6x
#else
    return 1.0f / x;
#endif
}

__device__ __forceinline__ float per_loss(float r1, float r2, int d) {
    float ratio = r1 * rcp_fast(r2 + EPS_F);
    float rinv  = r2 * rcp_fast(r1 + EPS_F);
    float l1 = (ratio > INVB_F) ? (ratio - INVB_F + (B_F - rinv)) : 0.0f;
    float l2 = (ratio < B_F)    ? (B_F - ratio + (rinv - INVB_F)) : 0.0f;
    float l0 = (ratio > BR_F)   ? (ratio - BR_F + (BL_F - rinv))
             : ((ratio < BL_F)  ? (BL_F - ratio + (rinv - BR_F)) : 0.0f);
    return (d == 1) ? l1 : ((d == 2) ? l2 : l0);
}

// ---- pipeline building blocks (each followed by sched_barrier(0) at the
// call site so the compiler cannot sink issues down to their consumers) ----

__device__ __forceinline__ void load_c(ivec4 (&cc)[NB], const ivec4* __restrict__ coords,
                                       int tid, int T, int ofs) {
    #pragma unroll
    for (int k = 0; k < NB; ++k)
        cc[k] = __builtin_nontemporal_load(&coords[tid + (ofs + k) * T]);
}

__device__ __forceinline__ void load_dw(int (&dd)[NB], float (&ww)[NB],
                                        const int* __restrict__ darker,
                                        const float* __restrict__ weights,
                                        int tid, int T, int ofs) {
    #pragma unroll
    for (int k = 0; k < NB; ++k)
        dd[k] = __builtin_nontemporal_load(&darker[tid + (ofs + k) * T]);
    #pragma unroll
    for (int k = 0; k < NB; ++k)
        ww[k] = __builtin_nontemporal_load(&weights[tid + (ofs + k) * T]);
}

// Issue the byte-gathers for one round into q-registers. Divergent per-lane
// LDS/global split (keep if/else form: masked ds_read_u8 + global_load_ubyte,
// NOT a generic-pointer flat load).
__device__ __forceinline__ void gather_issue(const ivec4 (&cc)[NB],
        unsigned (&q1)[NB], unsigned (&q2)[NB],
        const unsigned char* lv, const unsigned char* __restrict__ vq) {
    #pragma unroll
    for (int k = 0; k < NB; ++k) {
        int i1 = cc[k].y * HW + cc[k].x;
        int i2 = cc[k].w * HW + cc[k].z;
        if (i1 < LDS_PIX) q1[k] = lv[i1]; else q1[k] = vq[i1];
        if (i2 < LDS_PIX) q2[k] = lv[i2]; else q2[k] = vq[i2];
    }
}

__device__ __forceinline__ void consume(const unsigned (&q1)[NB], const unsigned (&q2)[NB],
                                        const int (&dd)[NB], const float (&ww)[NB],
                                        float& acc) {
    #pragma unroll
    for (int k = 0; k < NB; ++k) {
        float r1 = (float)(q1[k] + 1) * (1.0f / 256.0f);
        float r2 = (float)(q2[k] + 1) * (1.0f / 256.0f);
        acc += ww[k] * per_loss(r1, r2, dd[k]);
    }
}

#define SBAR() __builtin_amdgcn_sched_barrier(0)

// amdgpu_waves_per_eu(4,4): PIN the allocator at 4 waves/EU (= the LDS-capped
// occupancy) -> 128-VGPR budget. launch_bounds' 2nd arg is only a MINIMUM;
// R2/R4 showed the allocator targeting max-occupancy anyway (64/32 VGPRs) and
// silently spilling 50-100 MB of scratch (WRITE_SIZE smoking gun).
__global__ __launch_bounds__(THREADS)
__attribute__((amdgpu_waves_per_eu(4, 4)))
void whdr_kernel(
        const unsigned char* __restrict__ vq,
        const ivec4* __restrict__ coords,
        const int*   __restrict__ darker,
        const float* __restrict__ weights,
        float*       __restrict__ out,
        int n) {
    __shared__ unsigned char lv[LDS_PIX];        // 160 KB -> 1 block/CU
    const int tid = blockIdx.x * THREADS + threadIdx.x;
    const int T   = BLOCKS * THREADS;            // 524288
    float acc = 0.0f;

    if (n == T * NB * 4) {
        // ---- steady-state: 4 rounds, streams A/B ping-pong (2 ahead),
        // gathers double-buffered (issued 1 round before consumption) ----
        ivec4 cA[NB], cB[NB];
        int   dA[NB], dB[NB];
        float wA[NB], wB[NB];
        unsigned qa1[NB], qa2[NB], qb1[NB], qb2[NB];

        load_c (cA, coords, tid, T, 0);
        load_dw(dA, wA, darker, weights, tid, T, 0);
        load_c (cB, coords, tid, T, NB);
        load_dw(dB, wB, darker, weights, tid, T, NB);
        {   // cooperative LDS fill: 160 B/thread, 16B coalesced
            const uint4* s4 = (const uint4*)vq;
            uint4* d4 = (uint4*)lv;
            #pragma unroll
            for (int j = threadIdx.x; j < LDS_PIX / 16; j += THREADS) d4[j] = s4[j];
        }
        __syncthreads();

        gather_issue(cA, qa1, qa2, lv, vq);            SBAR();  // G0
        // round 0
        gather_issue(cB, qb1, qb2, lv, vq);            SBAR();  // G1
        load_c (cA, coords, tid, T, 2 * NB);           SBAR();  // c(r2)
        consume(qa1, qa2, dA, wA, acc);                         // G0 (counted wait)
        load_dw(dA, wA, darker, weights, tid, T, 2 * NB); SBAR();
        // round 1
        gather_issue(cA, qa1, qa2, lv, vq);            SBAR();  // G2 from c(r2)
        load_c (cB, coords, tid, T, 3 * NB);           SBAR();  // c(r3)
        consume(qb1, qb2, dB, wB, acc);                         // G1
        load_dw(dB, wB, darker, weights, tid, T, 3 * NB); SBAR();
        // round 2
        gather_issue(cB, qb1, qb2, lv, vq);            SBAR();  // G3 from c(r3)
        consume(qa1, qa2, dA, wA, acc);                         // G2
        // round 3 (drain)
        consume(qb1, qb2, dB, wB, acc);                         // G3
    } else {
        // ---- generic fallback (any n) ----
        {
            const uint4* s4 = (const uint4*)vq;
            uint4* d4 = (uint4*)lv;
            for (int j = threadIdx.x; j < LDS_PIX / 16; j += THREADS) d4[j] = s4[j];
        }
        __syncthreads();
        const int TT = gridDim.x * THREADS;
        for (int i = tid; i < n; i += TT) {
            ivec4 c = coords[i];
            int i1 = c.y * HW + c.x, i2 = c.w * HW + c.z;
            unsigned a = (i1 < LDS_PIX) ? (unsigned)lv[i1] : (unsigned)vq[i1];
            unsigned b = (i2 < LDS_PIX) ? (unsigned)lv[i2] : (unsigned)vq[i2];
            float r1 = (float)(a + 1) * (1.0f / 256.0f);
            float r2 = (float)(b + 1) * (1.0f / 256.0f);
            acc += weights[i] * per_loss(r1, r2, darker[i]);
        }
    }

    // wave-64 shuffle reduction
    #pragma unroll
    for (int off = 32; off > 0; off >>= 1)
        acc += __shfl_down(acc, off, 64);
    // Reuse lv's LDS for the block reduction (table reads done; barrier
    // orders the reuse).
    __syncthreads();
    float* wsum = (float*)lv;
    int lane = threadIdx.x & 63;
    int wid  = threadIdx.x >> 6;                 // 16 waves
    if (lane == 0) wsum[wid] = acc;
    __syncthreads();
    if (threadIdx.x == 0) {
        float s = 0.0f;
        #pragma unroll
        for (int i = 0; i < THREADS / 64; ++i) s += wsum[i];
        atomicAdd(out, s / (float)n);            // n = 2^23 -> exact
    }
}

extern "C" void kernel_launch(void* const* d_in, const int* in_sizes, int n_in,
                              void* d_out, int out_size, void* d_ws, size_t ws_size,
                              hipStream_t stream) {
    const float* v_input = (const float*)d_in[0];  // (3,512,512) f32
    const ivec4* coords  = (const ivec4*)d_in[1];  // (N,4) i32
    const int*   darker  = (const int*)d_in[2];    // (N,) i32
    const float* weights = (const float*)d_in[3];  // (N,) f32
    float* out = (float*)d_out;
    unsigned char* vq = (unsigned char*)d_ws;      // 256 KB u8 v table
    int n = in_sizes[2];                           // N

    build_v<<<(NPIX + 255) / 256, 256, 0, stream>>>(v_input, vq, out);
    whdr_kernel<<<BLOCKS, THREADS, 0, stream>>>(vq, coords, darker, weights, out, n);
}